// Round 4
// baseline (354.585 us; speedup 1.0000x reference)
//
#include <hip/hip_runtime.h>
#include <math.h>
#include <stdint.h>

#define N_      64
#define M_      2080          // N*(N+1)/2
#define B_      32
#define TOPK_   5
#define NEIGH_  16
#define NEG_    16
#define TOTAL_  85            // TOPK*(NEIGHBOR+1)
#define KOUT_   101           // NEGATIVE + TOTAL
#define D_      512
#define NT_     1024
#define NWAVE_  16
#define CHUNK_  3             // compaction chunk: ceil(2080/1024)
#define NE_     3072          // radix element count (3 * NT_, >= M_, padded)
#define KPT_    3             // items per thread in radix

// Exclusive block scan via wave shfl + LDS combine. 3 barriers.
// After return, s_wsum[NWAVE_-1] holds the block total.
__device__ __forceinline__ int block_scan_excl(int v, int tid, int* s_wsum)
{
    __syncthreads();                       // protect s_wsum reuse
    const int lane = tid & 63;
    const int wave = tid >> 6;
    int x = v;
#pragma unroll
    for (int off = 1; off < 64; off <<= 1) {
        int y = __shfl_up(x, off);
        if (lane >= off) x += y;
    }
    if (lane == 63) s_wsum[wave] = x;
    __syncthreads();
    if (wave == 0) {
        int w = (lane < NWAVE_) ? s_wsum[lane] : 0;
#pragma unroll
        for (int off = 1; off < NWAVE_; off <<= 1) {
            int y = __shfl_up(w, off);
            if (lane >= off) w += y;
        }
        if (lane < NWAVE_) s_wsum[lane] = w;   // inclusive wave totals
    }
    __syncthreads();
    int base = (wave > 0) ? s_wsum[wave - 1] : 0;
    return base + x - v;                   // exclusive prefix
}

// ---------------------------------------------------------------------------
// Kernel 1: per-batch proposal selection. One block (1024 thr) per batch.
// Stable LSD radix sort (4x8-bit) + single-wave NMS.
// ---------------------------------------------------------------------------
__global__ __launch_bounds__(NT_) void select_kernel(
    const float* __restrict__ score_pred,   // [B,64,64]
    const float* __restrict__ offset_gt,    // [B,64,64,2]
    const float* __restrict__ tmap,         // [B,64,64]
    float* __restrict__ out_pse,            // [B*K,2]
    float* __restrict__ out_off,            // [B*K,2]
    float* __restrict__ out_score)          // [B*K]
{
    __shared__ uint64_t s_a[NE_];                        // 24 KB
    __shared__ uint64_t s_b[NE_];                        // 24 KB
    __shared__ __align__(16) int s_cnt[256 * 48];        // 48 KB
    __shared__ int s_dbase[256];
    __shared__ unsigned char s_r[M_], s_c[M_];
    __shared__ unsigned char sm_s[M_], sm_e[M_];         // sorted moments
    __shared__ unsigned char s_sup[M_], s_sel[M_];
    __shared__ int s_unsupidx[M_];
    __shared__ int s_selidx[TOTAL_];
    __shared__ int s_wsum[NWAVE_];

    const int b    = blockIdx.x;
    const int tid  = threadIdx.x;
    const int lane = tid & 63;
    const int wav  = tid >> 6;
    const uint64_t ltmask = (1ULL << lane) - 1ULL;

    // ---- m -> (r,c) triangle table ----
    if (tid < N_) {
        int r  = tid;
        int rs = r * N_ - (r * (r - 1)) / 2;
        for (int k = 0; k < N_ - r; ++k) {
            s_r[rs + k] = (unsigned char)r;
            s_c[rs + k] = (unsigned char)(r + k);
        }
    }
    __syncthreads();

    // ---- load scores, pack sortable uint64 (key<<32 | idx) ----
    // ascending uint64 == descending score; LSD stability -> ties keep
    // ascending original idx (exactly stable argsort(-scores)).
    const float* sp = score_pred + (size_t)b * N_ * N_;
#pragma unroll
    for (int k = 0; k < KPT_; ++k) {
        int g = k * NT_ + tid;
        uint64_t kv;
        if (g < M_) {
            uint32_t fb  = __float_as_uint(sp[s_r[g] * N_ + s_c[g]]);
            uint32_t ord = (fb & 0x80000000u) ? ~fb : (fb | 0x80000000u);
            uint32_t dk  = ~ord;                        // descending map
            kv = ((uint64_t)dk << 32) | (uint32_t)g;
        } else {
            kv = ~0ULL;                                 // pad: sorts last
        }
        s_a[g] = kv;
    }

    // ---- 4-pass stable LSD radix sort on the 32-bit key (high word) ----
    uint64_t* cur = s_a;
    uint64_t* dst = s_b;
#pragma unroll
    for (int pass = 0; pass < 4; ++pass) {
        const int shift = 32 + 8 * pass;
        __syncthreads();                    // prev scatter visible; s_cnt free

        // zero counts (12288 ints, int4 stores)
        {
            int4* z = (int4*)s_cnt;
#pragma unroll
            for (int q = 0; q < 3; ++q)
                z[q * NT_ + tid] = make_int4(0, 0, 0, 0);
        }

        // phase1a: read own items (positions k*NT_+tid), digits
        uint64_t kv[KPT_];
        int dg[KPT_], rk[KPT_];
#pragma unroll
        for (int k = 0; k < KPT_; ++k) {
            kv[k] = cur[k * NT_ + tid];
            dg[k] = (int)((kv[k] >> shift) & 0xFF);
        }
        __syncthreads();                    // zeroing complete

        // phase1b: per-wave match masks (8 ballots), rank in wave, counts.
        // Position order = (k, wave, lane) lexicographic == slot order.
#pragma unroll
        for (int k = 0; k < KPT_; ++k) {
            int d = dg[k];
            uint64_t m = ~0ULL;
#pragma unroll
            for (int bit = 0; bit < 8; ++bit) {
                uint64_t bal = __ballot((d >> bit) & 1);
                m &= ((d >> bit) & 1) ? bal : ~bal;
            }
            rk[k] = __popcll(m & ltmask);
            if (rk[k] == 0)
                s_cnt[d * 48 + k * 16 + wav] = __popcll(m);
        }
        __syncthreads();                    // counts visible

        // phase2: per-digit exclusive prefix over 48 (k,w) slots + totals
        int dig_tot = 0, dig_incl = 0;
        if (tid < 256) {
            int vals[48];
#pragma unroll
            for (int q = 0; q < 48; ++q) vals[q] = s_cnt[tid * 48 + q];
            int run = 0;
#pragma unroll
            for (int q = 0; q < 48; ++q) {
                int c = vals[q];
                s_cnt[tid * 48 + q] = run;
                run += c;
            }
            dig_tot  = run;
            dig_incl = run;
#pragma unroll
            for (int off = 1; off < 64; off <<= 1) {
                int y = __shfl_up(dig_incl, off);
                if (lane >= off) dig_incl += y;
            }
            if (lane == 63) s_wsum[wav] = dig_incl;     // wav in 0..3
        }
        __syncthreads();
        if (tid < 256) {
            int base = 0;
#pragma unroll
            for (int q = 0; q < 4; ++q)
                if (q < wav) base += s_wsum[q];
            s_dbase[tid] = base + dig_incl - dig_tot;   // exclusive digit base
        }
        __syncthreads();

        // phase3: stable scatter
#pragma unroll
        for (int k = 0; k < KPT_; ++k) {
            int d   = dg[k];
            int off = s_dbase[d] + s_cnt[d * 48 + k * 16 + wav] + rk[k];
            dst[off] = kv[k];
        }
        uint64_t* t = cur; cur = dst; dst = t;          // 4 swaps -> cur==s_a
    }
    __syncthreads();

    // ---- sorted moments + init state ----
    for (int jj = tid; jj < M_; jj += NT_) {
        int o = (int)(uint32_t)cur[jj];
        sm_s[jj] = s_r[o];
        sm_e[jj] = (unsigned char)(s_c[o] + 1);
        s_sup[jj] = 0;
        s_sel[jj] = 0;
        s_unsupidx[jj] = M_ - 1;
    }
    if (tid < TOTAL_) s_selidx[tid] = M_ - 1;
    __syncthreads();

    // ---- NMS: wave 0 only, wave-synchronous (no block barriers inside) ----
    if (tid < 64) {
        volatile unsigned char* vsup = s_sup;
        volatile unsigned char* vsel = s_sel;
        int i = 0, cnt = 0;                 // i == current free pivot
        for (;;) {
            // process pivot i (guaranteed free, i < M_-1)
            const int si = sm_s[i], ei = sm_e[i];
            int run = 0;
#pragma unroll 1
            for (int q = 0; q < (M_ + 63) / 64; ++q) {
                int jj = q * 64 + lane;
                bool match = false;
                if (jj < M_ && jj > i) {
                    int s = sm_s[jj], e = sm_e[jj];
                    int inter = (e < ei ? e : ei) - (s > si ? s : si);
                    int uni   = (e > ei ? e : ei) - (s < si ? s : si);
                    match = (inter > 0 && 2 * inter > uni);   // iou > 0.5
                }
                uint64_t bal = __ballot(match);
                if (match) {
                    int pre = run + __popcll(bal & ltmask);
                    vsup[jj] = 1;
                    if (pre < NEIGH_) vsel[jj] = 1;     // cumsum(mask) <= 16
                }
                run += __popcll(bal);
            }
            if (lane == 0) { vsup[i] = 1; vsel[i] = 1; }
            ++cnt;
            if (cnt >= TOPK_) break;
            // find next free position in (i, M_-1)
            int next = -1;
            int base = i + 1;
            while (base < M_ - 1) {
                int jj = base + lane;
                bool freep = (jj < M_ - 1) && (vsup[jj] == 0);
                uint64_t bal = __ballot(freep);
                if (bal) { next = base + (__ffsll((long long)bal) - 1); break; }
                base += 64;
            }
            if (next < 0) break;
            i = next;
        }
    }
    __syncthreads();

    // ---- sel compaction ----
    const int j0 = tid * CHUNK_;
    int n_sel, n_unsup;
    {
        int localcnt = 0;
#pragma unroll
        for (int t = 0; t < CHUNK_; ++t) {
            int jj = j0 + t;
            if (jj < M_) localcnt += s_sel[jj];
        }
        int run = block_scan_excl(localcnt, tid, s_wsum);
        n_sel = s_wsum[NWAVE_ - 1];
#pragma unroll
        for (int t = 0; t < CHUNK_; ++t) {
            int jj = j0 + t;
            if (jj < M_ && s_sel[jj]) {
                if (run < TOTAL_) s_selidx[run] = jj;
                ++run;
            }
        }
    }
    // ---- unsup compaction ----
    {
        int localcnt = 0;
#pragma unroll
        for (int t = 0; t < CHUNK_; ++t) {
            int jj = j0 + t;
            if (jj < M_) localcnt += (s_sup[jj] == 0);
        }
        int run = block_scan_excl(localcnt, tid, s_wsum);
        n_unsup = s_wsum[NWAVE_ - 1];
#pragma unroll
        for (int t = 0; t < CHUNK_; ++t) {
            int jj = j0 + t;
            if (jj < M_ && s_sup[jj] == 0) {
                s_unsupidx[run] = jj;
                ++run;
            }
        }
    }
    __syncthreads();

    // ---- final 101 indices + small outputs ----
    if (tid < KOUT_) {
        int idx_sorted;
        if (tid < NEG_) {
            int t = n_unsup - 1 - tid;
            if (t < 0) t = 0;
            idx_sorted = s_unsupidx[t];
        } else {
            int p   = tid - NEG_;
            int pad = TOTAL_ - n_sel;
            idx_sorted = (p < pad) ? s_unsupidx[p] : s_selidx[p - pad];
        }
        int o = (int)(uint32_t)cur[idx_sorted];   // original proposal index
        int r = s_r[o], c = s_c[o];
        int gk = b * KOUT_ + tid;
        out_pse[2 * gk + 0] = (float)r;
        out_pse[2 * gk + 1] = (float)(c + 1);
        const float* og = offset_gt + ((size_t)b * N_ * N_ + r * N_ + c) * 2;
        out_off[2 * gk + 0] = og[0];
        out_off[2 * gk + 1] = og[1];
        out_score[gk] = tmap[(size_t)b * N_ * N_ + r * N_ + c];
    }
}

// ---------------------------------------------------------------------------
// Kernel 2: gather prop_feature rows (one block per output row, float4 copy).
// ---------------------------------------------------------------------------
__global__ __launch_bounds__(128) void gather_kernel(
    const float* __restrict__ map2d,        // [B,64,64,512]
    const float* __restrict__ out_pse,      // [B*K,2]
    float* __restrict__ out_feat)           // [B*K,512]
{
    int gk = blockIdx.x;
    int b  = gk / KOUT_;
    int r  = (int)out_pse[2 * gk + 0];
    int c  = (int)out_pse[2 * gk + 1] - 1;
    const float4* src = (const float4*)(map2d + ((size_t)b * N_ * N_ + r * N_ + c) * D_);
    float4*       dst = (float4*)(out_feat + (size_t)gk * D_);
    dst[threadIdx.x] = src[threadIdx.x];
}

extern "C" void kernel_launch(void* const* d_in, const int* in_sizes, int n_in,
                              void* d_out, int out_size, void* d_ws, size_t ws_size,
                              hipStream_t stream)
{
    const float* score_pred = (const float*)d_in[0];
    // d_in[1] = map2d_mask (deterministic triu mask, unused)
    const float* map2d      = (const float*)d_in[2];
    const float* offset_gt  = (const float*)d_in[3];
    const float* tmap       = (const float*)d_in[4];

    float* out       = (float*)d_out;
    float* out_feat  = out;                                   // [3232,512]
    float* out_pse   = out_feat + (size_t)B_ * KOUT_ * D_;    // [3232,2]
    float* out_off   = out_pse  + (size_t)B_ * KOUT_ * 2;     // [3232,2]
    float* out_score = out_off  + (size_t)B_ * KOUT_ * 2;     // [3232]

    select_kernel<<<B_, NT_, 0, stream>>>(score_pred, offset_gt, tmap,
                                          out_pse, out_off, out_score);
    gather_kernel<<<B_ * KOUT_, 128, 0, stream>>>(map2d, out_pse, out_feat);
}

// Round 5
// 346.749 us; speedup vs baseline: 1.0226x; 1.0226x over previous
//
#include <hip/hip_runtime.h>
#include <math.h>
#include <stdint.h>

#define N_      64
#define M_      2080          // N*(N+1)/2
#define SORTN   4096
#define B_      32
#define TOPK_   5
#define NEIGH_  16
#define NEG_    16
#define TOTAL_  85            // TOPK*(NEIGHBOR+1)
#define KOUT_   101           // NEGATIVE + TOTAL
#define D_      512
#define NT_     1024
#define NWAVE_  (NT_ / 64)    // 16
#define CHUNK_  3             // ceil(2080/1024)

// Exclusive block scan via wave shfl + 16-entry LDS combine. 3 barriers.
// After return, s_wsum[NWAVE_-1] holds the block total (stable until the
// next call's leading barrier).
__device__ __forceinline__ int block_scan_excl(int v, int tid, int* s_wsum)
{
    __syncthreads();                       // protect s_wsum reuse
    const int lane = tid & 63;
    const int wave = tid >> 6;
    int x = v;
#pragma unroll
    for (int off = 1; off < 64; off <<= 1) {
        int y = __shfl_up(x, off);
        if (lane >= off) x += y;
    }
    if (lane == 63) s_wsum[wave] = x;
    __syncthreads();
    if (wave == 0) {
        int w = (lane < NWAVE_) ? s_wsum[lane] : 0;
#pragma unroll
        for (int off = 1; off < NWAVE_; off <<= 1) {
            int y = __shfl_up(w, off);
            if (lane >= off) w += y;
        }
        if (lane < NWAVE_) s_wsum[lane] = w;   // inclusive wave totals
    }
    __syncthreads();
    int base = (wave > 0) ? s_wsum[wave - 1] : 0;
    return base + x - v;                   // exclusive prefix
}

// ---------------------------------------------------------------------------
// Kernel 1: per-batch proposal selection. One block (1024 thr) per batch.
// ---------------------------------------------------------------------------
__global__ __launch_bounds__(NT_) void select_kernel(
    const float* __restrict__ score_pred,   // [B,64,64]
    const float* __restrict__ offset_gt,    // [B,64,64,2]
    const float* __restrict__ tmap,         // [B,64,64]
    float* __restrict__ out_pse,            // [B*K,2]
    float* __restrict__ out_off,            // [B*K,2]
    float* __restrict__ out_score)          // [B*K]
{
    __shared__ uint64_t s_kv[SORTN];                 // 32 KB: key<<32 | idx
    __shared__ unsigned char s_r[M_], s_c[M_];
    __shared__ unsigned char sm_s[M_], sm_e[M_];     // sorted moments
    __shared__ unsigned char s_sup[M_], s_sel[M_];
    __shared__ int s_unsupidx[M_];
    __shared__ int s_selidx[TOTAL_];
    __shared__ int s_wsum[NWAVE_];

    const int b   = blockIdx.x;
    const int tid = threadIdx.x;

    // ---- m -> (r,c) triangle table ----
    if (tid < N_) {
        int r  = tid;
        int rs = r * N_ - (r * (r - 1)) / 2;
        for (int k = 0; k < N_ - r; ++k) {
            s_r[rs + k] = (unsigned char)r;
            s_c[rs + k] = (unsigned char)(r + k);
        }
    }
    __syncthreads();

    // ---- load scores, pack sortable uint64 keys ----
    // ascending uint64 sort == descending score, ties ascending original idx
    const float* sp = score_pred + (size_t)b * N_ * N_;
    for (int m = tid; m < SORTN; m += NT_) {
        uint64_t kv;
        if (m < M_) {
            int r = s_r[m], c = s_c[m];
            uint32_t fb  = __float_as_uint(sp[r * N_ + c]);
            uint32_t ord = (fb & 0x80000000u) ? ~fb : (fb | 0x80000000u); // ascending map
            uint32_t dk  = ~ord;                                          // descending
            kv = ((uint64_t)dk << 32) | (uint32_t)m;
        } else {
            kv = ~0ULL;                     // pad: sorts to the end
        }
        s_kv[m] = kv;
    }
    __syncthreads();

    // ---- bitonic sort (ascending uint64), 2 pairs per thread per pass ----
    for (int kk = 2; kk <= SORTN; kk <<= 1) {
        for (int j = kk >> 1; j > 0; j >>= 1) {
            const int jm = j - 1;
            // pair p0 = tid, p1 = tid + NT_ — unrolled for ILP
            int p0 = tid;
            int p1 = tid + NT_;
            int i0 = ((p0 & ~jm) << 1) | (p0 & jm);
            int i1 = ((p1 & ~jm) << 1) | (p1 & jm);
            uint64_t a0 = s_kv[i0], b0 = s_kv[i0 + j];
            uint64_t a1 = s_kv[i1], b1 = s_kv[i1 + j];
            bool up0 = ((i0 & kk) == 0);
            bool up1 = ((i1 & kk) == 0);
            bool sw0 = up0 ? (a0 > b0) : (a0 < b0);
            bool sw1 = up1 ? (a1 > b1) : (a1 < b1);
            if (sw0) { s_kv[i0] = b0; s_kv[i0 + j] = a0; }
            if (sw1) { s_kv[i1] = b1; s_kv[i1 + j] = a1; }
            __syncthreads();
        }
    }

    // ---- sorted moments + init ----
    for (int jj = tid; jj < M_; jj += NT_) {
        int o = (int)(uint32_t)s_kv[jj];
        sm_s[jj] = s_r[o];
        sm_e[jj] = (unsigned char)(s_c[o] + 1);
        s_sup[jj] = 0;
        s_sel[jj] = 0;
        s_unsupidx[jj] = M_ - 1;
    }
    if (tid < TOTAL_) s_selidx[tid] = M_ - 1;
    __syncthreads();

    // ---- NMS while-loop (block-uniform control flow) ----
    const int j0 = tid * CHUNK_;
    int i = 0, cnt = 0;
    while (cnt < TOPK_ && i < M_ - 1) {
        bool freei = (s_sup[i] == 0);
        if (freei) {
            const int si = sm_s[i], ei = sm_e[i];
            unsigned int mkbits = 0;
            int localcnt = 0;
#pragma unroll
            for (int t = 0; t < CHUNK_; ++t) {
                int jj = j0 + t;
                if (jj < M_ && jj > i) {
                    int s = sm_s[jj], e = sm_e[jj];
                    int inter = (e < ei ? e : ei) - (s > si ? s : si);
                    int uni   = (e > ei ? e : ei) - (s < si ? s : si);
                    if (inter > 0 && 2 * inter > uni) {   // iou > 0.5, exact
                        mkbits |= (1u << t);
                        ++localcnt;
                    }
                }
            }
            int run = block_scan_excl(localcnt, tid, s_wsum);
#pragma unroll
            for (int t = 0; t < CHUNK_; ++t) {
                if (mkbits & (1u << t)) {
                    int jj = j0 + t;
                    s_sup[jj] = 1;
                    if (run < NEIGH_) s_sel[jj] = 1;     // cumsum(mask) <= 16
                    ++run;
                }
            }
            if (tid == 0) { s_sup[i] = 1; s_sel[i] = 1; }
            ++cnt;
        }
        ++i;
        __syncthreads();
    }

    // ---- sel compaction ----
    int n_sel, n_unsup;
    {
        int localcnt = 0;
#pragma unroll
        for (int t = 0; t < CHUNK_; ++t) {
            int jj = j0 + t;
            if (jj < M_) localcnt += s_sel[jj];
        }
        int run = block_scan_excl(localcnt, tid, s_wsum);
        n_sel = s_wsum[NWAVE_ - 1];
#pragma unroll
        for (int t = 0; t < CHUNK_; ++t) {
            int jj = j0 + t;
            if (jj < M_ && s_sel[jj]) {
                if (run < TOTAL_) s_selidx[run] = jj;
                ++run;
            }
        }
    }
    // ---- unsup compaction ----
    {
        int localcnt = 0;
#pragma unroll
        for (int t = 0; t < CHUNK_; ++t) {
            int jj = j0 + t;
            if (jj < M_) localcnt += (s_sup[jj] == 0);
        }
        int run = block_scan_excl(localcnt, tid, s_wsum);
        n_unsup = s_wsum[NWAVE_ - 1];
#pragma unroll
        for (int t = 0; t < CHUNK_; ++t) {
            int jj = j0 + t;
            if (jj < M_ && s_sup[jj] == 0) {
                s_unsupidx[run] = jj;
                ++run;
            }
        }
    }
    __syncthreads();

    // ---- final 101 indices + small outputs ----
    if (tid < KOUT_) {
        int idx_sorted;
        if (tid < NEG_) {
            int t = n_unsup - 1 - tid;
            if (t < 0) t = 0;
            idx_sorted = s_unsupidx[t];
        } else {
            int p   = tid - NEG_;
            int pad = TOTAL_ - n_sel;
            idx_sorted = (p < pad) ? s_unsupidx[p] : s_selidx[p - pad];
        }
        int o = (int)(uint32_t)s_kv[idx_sorted];   // original proposal index
        int r = s_r[o], c = s_c[o];
        int gk = b * KOUT_ + tid;
        out_pse[2 * gk + 0] = (float)r;
        out_pse[2 * gk + 1] = (float)(c + 1);
        const float* og = offset_gt + ((size_t)b * N_ * N_ + r * N_ + c) * 2;
        out_off[2 * gk + 0] = og[0];
        out_off[2 * gk + 1] = og[1];
        out_score[gk] = tmap[(size_t)b * N_ * N_ + r * N_ + c];
    }
}

// ---------------------------------------------------------------------------
// Kernel 2: gather prop_feature rows (one block per output row, float4 copy).
// ---------------------------------------------------------------------------
__global__ __launch_bounds__(128) void gather_kernel(
    const float* __restrict__ map2d,        // [B,64,64,512]
    const float* __restrict__ out_pse,      // [B*K,2]
    float* __restrict__ out_feat)           // [B*K,512]
{
    int gk = blockIdx.x;
    int b  = gk / KOUT_;
    int r  = (int)out_pse[2 * gk + 0];
    int c  = (int)out_pse[2 * gk + 1] - 1;
    const float4* src = (const float4*)(map2d + ((size_t)b * N_ * N_ + r * N_ + c) * D_);
    float4*       dst = (float4*)(out_feat + (size_t)gk * D_);
    dst[threadIdx.x] = src[threadIdx.x];
}

extern "C" void kernel_launch(void* const* d_in, const int* in_sizes, int n_in,
                              void* d_out, int out_size, void* d_ws, size_t ws_size,
                              hipStream_t stream)
{
    const float* score_pred = (const float*)d_in[0];
    // d_in[1] = map2d_mask (deterministic triu mask, unused)
    const float* map2d      = (const float*)d_in[2];
    const float* offset_gt  = (const float*)d_in[3];
    const float* tmap       = (const float*)d_in[4];

    float* out       = (float*)d_out;
    float* out_feat  = out;                                   // [3232,512]
    float* out_pse   = out_feat + (size_t)B_ * KOUT_ * D_;    // [3232,2]
    float* out_off   = out_pse  + (size_t)B_ * KOUT_ * 2;     // [3232,2]
    float* out_score = out_off  + (size_t)B_ * KOUT_ * 2;     // [3232]

    select_kernel<<<B_, NT_, 0, stream>>>(score_pred, offset_gt, tmap,
                                          out_pse, out_off, out_score);
    gather_kernel<<<B_ * KOUT_, 128, 0, stream>>>(map2d, out_pse, out_feat);
}